// Round 1
// baseline (429.310 us; speedup 1.0000x reference)
//
#include <hip/hip_runtime.h>
#include <stdint.h>

#define M_ROWS 4096
#define N_COLS 16384
#define K_HARD 163          // int(0.01 * (16384 - 1))
#define DELTA_W 5.0f
#define CAP    5376         // candidate buffer (elements >= 1.0f: ~2600 +- 46 per row)
#define NB1    4096         // level-1 radix bins (top 12 bits of key)
#define NB2    1024         // level-2/3 bins (10 bits each)
#define BLOCK  256

// monotonic float->uint key: unsigned compare == float compare
__device__ __forceinline__ uint32_t f2key(float x) {
    uint32_t u = __float_as_uint(x);
    return (u & 0x80000000u) ? ~u : (u | 0x80000000u);
}
__device__ __forceinline__ float key2f(uint32_t k) {
    uint32_t u = (k & 0x80000000u) ? (k & 0x7fffffffu) : ~k;
    return __uint_as_float(u);
}
__device__ __forceinline__ float softplus_f(float x) {
    return fmaxf(x, 0.0f) + log1pf(__expf(-fabsf(x)));
}

// Parallel pivot finder: given hist[0..nb) (ascending key order), find bin P
// s.t. count(bins > P) < K <= count(bins >= P). Writes P to *pivot and
// K - count(bins > P) (elements still needed from bin P) to *krem.
// All BLOCK threads must call (uniform). Uses part[BLOCK] scratch.
__device__ void pivot_scan(const uint32_t* hist, int nb, int K,
                           int* part, int* pivot, int* krem) {
    const int t = threadIdx.x;
    const int bpt = nb / BLOCK;
    const int base = t * bpt;
    int mypart = 0;
    for (int i = 0; i < bpt; ++i) mypart += (int)hist[base + i];
    part[t] = mypart;
    __syncthreads();
    // inclusive suffix scan (Hillis-Steele)
    for (int off = 1; off < BLOCK; off <<= 1) {
        int v = part[t];
        if (t + off < BLOCK) v += part[t + off];
        __syncthreads();
        part[t] = v;
        __syncthreads();
    }
    const int above = part[t] - mypart;   // sum of segments strictly above t
    if (above < K && above + mypart >= K) {
        int running = above;
        for (int b = base + bpt - 1; b >= base; --b) {
            int c = (int)hist[b];
            if (running < K && running + c >= K) { *pivot = b; *krem = K - running; }
            running += c;
        }
    }
    __syncthreads();
}

__global__ __launch_bounds__(BLOCK) void mmcl_kernel(
        const float* __restrict__ inputs,
        const int* __restrict__ targets,
        float* __restrict__ out) {
    __shared__ uint32_t s_hist[NB1];
    __shared__ uint32_t s_cand[CAP];
    __shared__ int s_part[BLOCK];
    __shared__ int s_ncand;
    __shared__ int s_pivot;
    __shared__ int s_krem;
    __shared__ float s_pos;
    __shared__ float s_wsum[BLOCK / 64];

    const int row = blockIdx.x;
    const int t = threadIdx.x;
    const int lane = t & 63;
    const float* rowp = inputs + (size_t)row * N_COLS;
    const int target = targets[row];

    for (int i = t; i < NB1; i += BLOCK) s_hist[i] = 0;
    if (t == 0) s_ncand = 0;
    __syncthreads();

    const uint32_t KEY_MIN = 0xBF800000u;   // f2key(1.0f)

    // ---- single HBM pass: load, transform, compact candidates ----
    const float4* rp4 = (const float4*)rowp;
    for (int it = 0; it < N_COLS / (BLOCK * 4); ++it) {
        const int v4 = it * BLOCK + t;
        const float4 v = rp4[v4];
        const int j0 = v4 * 4;
        const float vals[4] = {v.x, v.y, v.z, v.w};
#pragma unroll
        for (int c = 0; c < 4; ++c) {
            const int j = j0 + c;
            const float x = vals[c];
            const bool is_t = (j == target);
            if (is_t) s_pos = x;
            const uint32_t key = f2key(x);
            const bool pred = (!is_t) && (key >= KEY_MIN);
            const unsigned long long mask = __ballot(pred);
            if (mask) {   // wave-uniform
                const int leader = __ffsll((unsigned long long)mask) - 1;
                const int cnt = __popcll(mask);
                int basei = 0;
                if (lane == leader) basei = atomicAdd(&s_ncand, cnt);
                basei = __shfl(basei, leader);
                if (pred) {
                    const int off = basei +
                        (int)__popcll(mask & ((1ULL << lane) - 1ULL));
                    if (off < CAP) s_cand[off] = key;
                }
            }
        }
    }
    __syncthreads();
    const int ncand = s_ncand;
    const bool fast = (ncand >= K_HARD) && (ncand <= CAP);   // block-uniform

    float local = 0.0f;
    uint32_t T;
    int tie;

    if (fast) {
        // level 1: top 12 bits over candidates
        for (int i = t; i < ncand; i += BLOCK)
            atomicAdd(&s_hist[s_cand[i] >> 20], 1u);
        __syncthreads();
        pivot_scan(s_hist, NB1, K_HARD, s_part, &s_pivot, &s_krem);
        const int p1 = s_pivot, k1 = s_krem;

        // level 2: bits 19:10 among prefix matches
        for (int i = t; i < NB2; i += BLOCK) s_hist[i] = 0;
        __syncthreads();
        for (int i = t; i < ncand; i += BLOCK) {
            const uint32_t k = s_cand[i];
            if ((int)(k >> 20) == p1) atomicAdd(&s_hist[(k >> 10) & 1023u], 1u);
        }
        __syncthreads();
        pivot_scan(s_hist, NB2, k1, s_part, &s_pivot, &s_krem);
        const int p2 = s_pivot, k2 = s_krem;
        const uint32_t pref2 = ((uint32_t)p1 << 10) | (uint32_t)p2;

        // level 3: bits 9:0
        for (int i = t; i < NB2; i += BLOCK) s_hist[i] = 0;
        __syncthreads();
        for (int i = t; i < ncand; i += BLOCK) {
            const uint32_t k = s_cand[i];
            if ((k >> 10) == pref2) atomicAdd(&s_hist[k & 1023u], 1u);
        }
        __syncthreads();
        pivot_scan(s_hist, NB2, k2, s_part, &s_pivot, &s_krem);
        T = (pref2 << 10) | (uint32_t)s_pivot;
        tie = s_krem;

        for (int i = t; i < ncand; i += BLOCK) {
            const uint32_t k = s_cand[i];
            if (k > T) local += softplus_f(key2f(k));
        }
    } else {
        // ---- generic exact fallback: radix select re-reading global ----
        for (int j = t; j < N_COLS; j += BLOCK) {
            if (j == target) continue;
            atomicAdd(&s_hist[f2key(rowp[j]) >> 20], 1u);
        }
        __syncthreads();
        pivot_scan(s_hist, NB1, K_HARD, s_part, &s_pivot, &s_krem);
        const int p1 = s_pivot, k1 = s_krem;

        for (int i = t; i < NB2; i += BLOCK) s_hist[i] = 0;
        __syncthreads();
        for (int j = t; j < N_COLS; j += BLOCK) {
            if (j == target) continue;
            const uint32_t k = f2key(rowp[j]);
            if ((int)(k >> 20) == p1) atomicAdd(&s_hist[(k >> 10) & 1023u], 1u);
        }
        __syncthreads();
        pivot_scan(s_hist, NB2, k1, s_part, &s_pivot, &s_krem);
        const int p2 = s_pivot, k2 = s_krem;
        const uint32_t pref2 = ((uint32_t)p1 << 10) | (uint32_t)p2;

        for (int i = t; i < NB2; i += BLOCK) s_hist[i] = 0;
        __syncthreads();
        for (int j = t; j < N_COLS; j += BLOCK) {
            if (j == target) continue;
            const uint32_t k = f2key(rowp[j]);
            if ((k >> 10) == pref2) atomicAdd(&s_hist[k & 1023u], 1u);
        }
        __syncthreads();
        pivot_scan(s_hist, NB2, k2, s_part, &s_pivot, &s_krem);
        T = (pref2 << 10) | (uint32_t)s_pivot;
        tie = s_krem;

        for (int j = t; j < N_COLS; j += BLOCK) {
            if (j == target) continue;
            const uint32_t k = f2key(rowp[j]);
            if (k > T) local += softplus_f(key2f(k));
        }
    }

    // ---- block reduce + epilogue ----
    for (int off = 32; off > 0; off >>= 1) local += __shfl_down(local, off);
    if (lane == 0) s_wsum[t >> 6] = local;
    __syncthreads();
    if (t == 0) {
        float tot = 0.0f;
        for (int w = 0; w < BLOCK / 64; ++w) tot += s_wsum[w];
        tot += (float)tie * softplus_f(key2f(T));
        const float l_neg = tot / (float)K_HARD;
        const float l_pos = softplus_f(-s_pos);
        const float rowval = (DELTA_W * l_pos + l_neg) * (1.0f / (float)M_ROWS);
        atomicAdd(out, rowval);
    }
}

__global__ void mmcl_zero_out(float* out) { out[0] = 0.0f; }

extern "C" void kernel_launch(void* const* d_in, const int* in_sizes, int n_in,
                              void* d_out, int out_size, void* d_ws, size_t ws_size,
                              hipStream_t stream) {
    const float* inputs = (const float*)d_in[0];
    const int* targets = (const int*)d_in[1];
    float* out = (float*)d_out;
    mmcl_zero_out<<<1, 1, 0, stream>>>(out);
    mmcl_kernel<<<M_ROWS, BLOCK, 0, stream>>>(inputs, targets, out);
}

// Round 2
// 400.253 us; speedup vs baseline: 1.0726x; 1.0726x over previous
//
#include <hip/hip_runtime.h>
#include <stdint.h>

#define M_ROWS 4096
#define N_COLS 16384
#define K_HARD 163          // int(0.01 * (16384 - 1))
#define DELTA_W 5.0f
#define CAP    1024         // candidates >= 2.0: mean ~373, std ~19 -> 34 sigma headroom
#define NB1    4096         // level-1 radix bins (top 12 bits of key)
#define NB2    1024         // level-2/3 bins (10 bits each)
#define BLOCK  256

// monotonic float->uint key: unsigned compare == float compare
__device__ __forceinline__ uint32_t f2key(float x) {
    uint32_t u = __float_as_uint(x);
    return u ^ (((int32_t)u >> 31) | 0x80000000u);
}
__device__ __forceinline__ float key2f(uint32_t k) {
    uint32_t u = (k & 0x80000000u) ? (k & 0x7fffffffu) : ~k;
    return __uint_as_float(u);
}
__device__ __forceinline__ float softplus_f(float x) {
    return fmaxf(x, 0.0f) + log1pf(__expf(-fabsf(x)));
}

#define KEY_MIN 0xC0000000u   // f2key(2.0f)

// Parallel pivot finder: hist[0..nb) in ascending key order; find bin P with
// count(bins > P) < K <= count(bins >= P). *pivot=P, *krem=K-count(bins>P).
// All BLOCK threads call (uniform).
__device__ void pivot_scan(const uint32_t* hist, int nb, int K,
                           int* part, int* pivot, int* krem) {
    const int t = threadIdx.x;
    const int bpt = nb / BLOCK;
    const int base = t * bpt;
    int mypart = 0;
    for (int i = 0; i < bpt; ++i) mypart += (int)hist[base + i];
    part[t] = mypart;
    __syncthreads();
    for (int off = 1; off < BLOCK; off <<= 1) {   // inclusive suffix scan
        int v = part[t];
        if (t + off < BLOCK) v += part[t + off];
        __syncthreads();
        part[t] = v;
        __syncthreads();
    }
    const int above = part[t] - mypart;
    if (above < K && above + mypart >= K) {
        int running = above;
        for (int b = base + bpt - 1; b >= base; --b) {
            int c = (int)hist[b];
            if (running < K && running + c >= K) { *pivot = b; *krem = K - running; }
            running += c;
        }
    }
    __syncthreads();
}

__global__ __launch_bounds__(BLOCK) void mmcl_kernel(
        const float* __restrict__ inputs,
        const int* __restrict__ targets,
        float* __restrict__ out) {
    __shared__ uint32_t s_hist[NB1];
    __shared__ uint32_t s_cand[CAP];
    __shared__ int s_part[BLOCK];
    __shared__ int s_ncand;
    __shared__ int s_found;
    __shared__ int s_pivot;
    __shared__ int s_krem;
    __shared__ float s_pos;
    __shared__ float s_wsum[BLOCK / 64];

    const int row = blockIdx.x;
    const int t = threadIdx.x;
    const int lane = t & 63;
    const float* rowp = inputs + (size_t)row * N_COLS;
    const int target = targets[row];

    for (int i = t; i < NB1; i += BLOCK) s_hist[i] = 0;
    if (t == 0) { s_ncand = 0; s_found = -1; s_pos = rowp[target]; }
    __syncthreads();

    // ---- single HBM pass: tight load + compare + rare compaction ----
    const float4* rp4 = (const float4*)rowp;
#pragma unroll 4
    for (int it = 0; it < N_COLS / (BLOCK * 4); ++it) {
        const float4 v = rp4[it * BLOCK + t];
        const uint32_t k0 = f2key(v.x), k1 = f2key(v.y),
                       k2 = f2key(v.z), k3 = f2key(v.w);
        if (k0 >= KEY_MIN) { int i = atomicAdd(&s_ncand, 1); if (i < CAP) s_cand[i] = k0; }
        if (k1 >= KEY_MIN) { int i = atomicAdd(&s_ncand, 1); if (i < CAP) s_cand[i] = k1; }
        if (k2 >= KEY_MIN) { int i = atomicAdd(&s_ncand, 1); if (i < CAP) s_cand[i] = k2; }
        if (k3 >= KEY_MIN) { int i = atomicAdd(&s_ncand, 1); if (i < CAP) s_cand[i] = k3; }
    }
    __syncthreads();

    // ---- remove the positive's key (one instance; bit-equal keys interchangeable)
    const int ncand_raw = s_ncand;
    const uint32_t tkey = f2key(s_pos);
    const bool no_ovf = (ncand_raw <= CAP);
    if (no_ovf && tkey >= KEY_MIN) {
        for (int i = t; i < ncand_raw; i += BLOCK)
            if (s_cand[i] == tkey) { atomicCAS(&s_found, -1, i); break; }
    }
    __syncthreads();
    if (t == 0 && s_found >= 0) {
        s_cand[s_found] = s_cand[ncand_raw - 1];
        s_ncand = ncand_raw - 1;
    }
    __syncthreads();
    const int ncand = s_ncand;
    const bool fast = no_ovf && (ncand >= K_HARD);   // block-uniform

    float local = 0.0f;
    uint32_t T;
    int tie;

    if (fast) {
        // level 1: top 12 bits
        for (int i = t; i < ncand; i += BLOCK)
            atomicAdd(&s_hist[s_cand[i] >> 20], 1u);
        __syncthreads();
        pivot_scan(s_hist, NB1, K_HARD, s_part, &s_pivot, &s_krem);
        const int p1 = s_pivot, k1r = s_krem;

        // level 2: bits 19:10 among prefix matches
        for (int i = t; i < NB2; i += BLOCK) s_hist[i] = 0;
        __syncthreads();
        for (int i = t; i < ncand; i += BLOCK) {
            const uint32_t k = s_cand[i];
            if ((int)(k >> 20) == p1) atomicAdd(&s_hist[(k >> 10) & 1023u], 1u);
        }
        __syncthreads();
        pivot_scan(s_hist, NB2, k1r, s_part, &s_pivot, &s_krem);
        const int p2 = s_pivot, k2r = s_krem;
        const uint32_t pref2 = ((uint32_t)p1 << 10) | (uint32_t)p2;

        // level 3: bits 9:0
        for (int i = t; i < NB2; i += BLOCK) s_hist[i] = 0;
        __syncthreads();
        for (int i = t; i < ncand; i += BLOCK) {
            const uint32_t k = s_cand[i];
            if ((k >> 10) == pref2) atomicAdd(&s_hist[k & 1023u], 1u);
        }
        __syncthreads();
        pivot_scan(s_hist, NB2, k2r, s_part, &s_pivot, &s_krem);
        T = (pref2 << 10) | (uint32_t)s_pivot;
        tie = s_krem;

        for (int i = t; i < ncand; i += BLOCK) {
            const uint32_t k = s_cand[i];
            if (k > T) local += softplus_f(key2f(k));
        }
    } else {
        // ---- generic exact fallback (never taken on N(0,1) data) ----
        for (int i = t; i < NB1; i += BLOCK) s_hist[i] = 0;
        __syncthreads();
        for (int j = t; j < N_COLS; j += BLOCK) {
            if (j == target) continue;
            atomicAdd(&s_hist[f2key(rowp[j]) >> 20], 1u);
        }
        __syncthreads();
        pivot_scan(s_hist, NB1, K_HARD, s_part, &s_pivot, &s_krem);
        const int p1 = s_pivot, k1r = s_krem;

        for (int i = t; i < NB2; i += BLOCK) s_hist[i] = 0;
        __syncthreads();
        for (int j = t; j < N_COLS; j += BLOCK) {
            if (j == target) continue;
            const uint32_t k = f2key(rowp[j]);
            if ((int)(k >> 20) == p1) atomicAdd(&s_hist[(k >> 10) & 1023u], 1u);
        }
        __syncthreads();
        pivot_scan(s_hist, NB2, k1r, s_part, &s_pivot, &s_krem);
        const int p2 = s_pivot, k2r = s_krem;
        const uint32_t pref2 = ((uint32_t)p1 << 10) | (uint32_t)p2;

        for (int i = t; i < NB2; i += BLOCK) s_hist[i] = 0;
        __syncthreads();
        for (int j = t; j < N_COLS; j += BLOCK) {
            if (j == target) continue;
            const uint32_t k = f2key(rowp[j]);
            if ((k >> 10) == pref2) atomicAdd(&s_hist[k & 1023u], 1u);
        }
        __syncthreads();
        pivot_scan(s_hist, NB2, k2r, s_part, &s_pivot, &s_krem);
        T = (pref2 << 10) | (uint32_t)s_pivot;
        tie = s_krem;

        for (int j = t; j < N_COLS; j += BLOCK) {
            if (j == target) continue;
            const uint32_t k = f2key(rowp[j]);
            if (k > T) local += softplus_f(key2f(k));
        }
    }

    // ---- block reduce + epilogue ----
    for (int off = 32; off > 0; off >>= 1) local += __shfl_down(local, off);
    if (lane == 0) s_wsum[t >> 6] = local;
    __syncthreads();
    if (t == 0) {
        float tot = 0.0f;
        for (int w = 0; w < BLOCK / 64; ++w) tot += s_wsum[w];
        tot += (float)tie * softplus_f(key2f(T));
        const float l_neg = tot / (float)K_HARD;
        const float l_pos = softplus_f(-s_pos);
        const float rowval = (DELTA_W * l_pos + l_neg) * (1.0f / (float)M_ROWS);
        atomicAdd(out, rowval);
    }
}

__global__ void mmcl_zero_out(float* out) { out[0] = 0.0f; }

extern "C" void kernel_launch(void* const* d_in, const int* in_sizes, int n_in,
                              void* d_out, int out_size, void* d_ws, size_t ws_size,
                              hipStream_t stream) {
    const float* inputs = (const float*)d_in[0];
    const int* targets = (const int*)d_in[1];
    float* out = (float*)d_out;
    mmcl_zero_out<<<1, 1, 0, stream>>>(out);
    mmcl_kernel<<<M_ROWS, BLOCK, 0, stream>>>(inputs, targets, out);
}

// Round 3
// 382.478 us; speedup vs baseline: 1.1224x; 1.0465x over previous
//
#include <hip/hip_runtime.h>
#include <stdint.h>

#define M_ROWS 4096
#define N_COLS 16384
#define K_HARD 163          // int(0.01 * (16384 - 1))
#define DELTA_W 5.0f
#define CAPW   256          // per-wave candidate cap (mean ~93, std ~9.5 -> 17 sigma)
#define NWAVE  4
#define CAP    (CAPW * NWAVE)
#define NB     1024         // radix bins per level
#define BLOCK  256

#define KEY_MIN  0xC0000000u   // f2key(2.0f)
#define BIN_BIAS 3072          // KEY_MIN >> 20

// monotonic float->uint key: unsigned compare == float compare
__device__ __forceinline__ uint32_t f2key(float x) {
    uint32_t u = __float_as_uint(x);
    return u ^ (uint32_t)(((int32_t)u >> 31) | 0x80000000u);
}
__device__ __forceinline__ float key2f(uint32_t k) {
    uint32_t u = (k & 0x80000000u) ? (k & 0x7fffffffu) : ~k;
    return __uint_as_float(u);
}
__device__ __forceinline__ float softplus_f(float x) {
    return fmaxf(x, 0.0f) + log1pf(__expf(-fabsf(x)));
}

// Parallel pivot finder: hist[0..NB) ascending key order; find bin P with
// count(bins > P) < K <= count(bins >= P). *pivot=P, *krem=K-count(bins>P).
__device__ void pivot_scan(const uint32_t* hist, int K,
                           int* part, int* pivot, int* krem) {
    const int t = threadIdx.x;
    const int bpt = NB / BLOCK;            // 4
    const int base = t * bpt;
    int mypart = 0;
    for (int i = 0; i < bpt; ++i) mypart += (int)hist[base + i];
    part[t] = mypart;
    __syncthreads();
    for (int off = 1; off < BLOCK; off <<= 1) {   // inclusive suffix scan
        int v = part[t];
        if (t + off < BLOCK) v += part[t + off];
        __syncthreads();
        part[t] = v;
        __syncthreads();
    }
    const int above = part[t] - mypart;
    if (above < K && above + mypart >= K) {
        int running = above;
        for (int b = base + bpt - 1; b >= base; --b) {
            int c = (int)hist[b];
            if (running < K && running + c >= K) { *pivot = b; *krem = K - running; }
            running += c;
        }
    }
    __syncthreads();
}

__global__ __launch_bounds__(BLOCK) void mmcl_kernel(
        const float* __restrict__ inputs,
        const int* __restrict__ targets,
        float* __restrict__ out) {
    __shared__ uint32_t s_hist[NB];
    __shared__ uint32_t s_cand[CAP];     // per-wave segments
    __shared__ uint32_t s_cand2[CAP];    // compacted
    __shared__ int s_part[BLOCK];
    __shared__ int s_cnt[NWAVE];
    __shared__ int s_found;
    __shared__ int s_pivot;
    __shared__ int s_krem;
    __shared__ float s_wsum[NWAVE];

    const int row = blockIdx.x;
    const int t = threadIdx.x;
    const int lane = t & 63;
    const int wid = t >> 6;
    const float* rowp = inputs + (size_t)row * N_COLS;
    const int target = targets[row];

    for (int i = t; i < NB; i += BLOCK) s_hist[i] = 0;
    if (t == 0) s_found = -1;

    // ---- single HBM pass: ballot-compaction, no LDS atomics ----
    uint32_t* wcand = s_cand + wid * CAPW;
    int wcount = 0;
    const float4* rp4 = (const float4*)rowp;
#pragma unroll 4
    for (int it = 0; it < N_COLS / (BLOCK * 4); ++it) {
        const float4 v = rp4[it * BLOCK + t];
        const float vals[4] = {v.x, v.y, v.z, v.w};
#pragma unroll
        for (int c = 0; c < 4; ++c) {
            const uint32_t k = f2key(vals[c]);
            const bool pred = (k >= KEY_MIN);
            const unsigned long long mask = __ballot(pred);
            if (pred) {
                const int below = __builtin_amdgcn_mbcnt_hi(
                    (uint32_t)(mask >> 32),
                    __builtin_amdgcn_mbcnt_lo((uint32_t)mask, 0));
                const int off = wcount + below;
                if (off < CAPW) wcand[off] = k;
            }
            wcount += (int)__popcll(mask);
        }
    }
    if (lane == 0) s_cnt[wid] = wcount;
    __syncthreads();

    const int c0 = s_cnt[0], c1 = s_cnt[1], c2 = s_cnt[2], c3 = s_cnt[3];
    const int total = c0 + c1 + c2 + c3;
    const bool no_ovf = (c0 <= CAPW) & (c1 <= CAPW) & (c2 <= CAPW) & (c3 <= CAPW);
    const int wbase = (wid > 0 ? c0 : 0) + (wid > 1 ? c1 : 0) + (wid > 2 ? c2 : 0);

    // positive logit: broadcast load (row just streamed -> cache hit)
    const float pos = rowp[target];
    const uint32_t tkey = f2key(pos);

    if (no_ovf) {
        // compact per-wave segments into s_cand2
        const int mycnt = s_cnt[wid];
        for (int i = lane; i < mycnt; i += 64) s_cand2[wbase + i] = wcand[i];
    }
    __syncthreads();

    // remove one instance of the positive's key (bit-equal keys interchangeable)
    if (no_ovf && tkey >= KEY_MIN) {
        for (int i = t; i < total; i += BLOCK)
            if (s_cand2[i] == tkey) { atomicCAS(&s_found, -1, i); break; }
    }
    __syncthreads();
    int ncand = total;
    if (s_found >= 0) {
        if (t == 0) s_cand2[s_found] = s_cand2[total - 1];
        ncand = total - 1;
    }
    __syncthreads();
    const bool fast = no_ovf && (ncand >= K_HARD);   // block-uniform

    float local = 0.0f;
    uint32_t T;
    int tie;

    if (fast) {
        // level 1: top 12 bits, biased (all keys >= KEY_MIN)
        for (int i = t; i < ncand; i += BLOCK)
            atomicAdd(&s_hist[(s_cand2[i] >> 20) - BIN_BIAS], 1u);
        __syncthreads();
        pivot_scan(s_hist, K_HARD, s_part, &s_pivot, &s_krem);
        const int p1b = s_pivot + BIN_BIAS, k1r = s_krem;

        // level 2: bits 19:10 among prefix matches
        for (int i = t; i < NB; i += BLOCK) s_hist[i] = 0;
        __syncthreads();
        for (int i = t; i < ncand; i += BLOCK) {
            const uint32_t k = s_cand2[i];
            if ((int)(k >> 20) == p1b) atomicAdd(&s_hist[(k >> 10) & 1023u], 1u);
        }
        __syncthreads();
        pivot_scan(s_hist, k1r, s_part, &s_pivot, &s_krem);
        const int p2 = s_pivot, k2r = s_krem;
        const uint32_t pref2 = ((uint32_t)p1b << 10) | (uint32_t)p2;

        // level 3: bits 9:0
        for (int i = t; i < NB; i += BLOCK) s_hist[i] = 0;
        __syncthreads();
        for (int i = t; i < ncand; i += BLOCK) {
            const uint32_t k = s_cand2[i];
            if ((k >> 10) == pref2) atomicAdd(&s_hist[k & 1023u], 1u);
        }
        __syncthreads();
        pivot_scan(s_hist, k2r, s_part, &s_pivot, &s_krem);
        T = (pref2 << 10) | (uint32_t)s_pivot;
        tie = s_krem;

        for (int i = t; i < ncand; i += BLOCK) {
            const uint32_t k = s_cand2[i];
            if (k > T) local += softplus_f(key2f(k));
        }
    } else {
        // ---- generic exact fallback (never taken on N(0,1) data) ----
        // 10+10+10-bit radix over full key range, re-reading global,
        // then a 2-bit serial resolve.
        for (int i = t; i < NB; i += BLOCK) s_hist[i] = 0;
        __syncthreads();
        for (int j = t; j < N_COLS; j += BLOCK) {
            if (j == target) continue;
            atomicAdd(&s_hist[f2key(rowp[j]) >> 22], 1u);
        }
        __syncthreads();
        pivot_scan(s_hist, K_HARD, s_part, &s_pivot, &s_krem);
        const int p1 = s_pivot, k1r = s_krem;

        for (int i = t; i < NB; i += BLOCK) s_hist[i] = 0;
        __syncthreads();
        for (int j = t; j < N_COLS; j += BLOCK) {
            if (j == target) continue;
            const uint32_t k = f2key(rowp[j]);
            if ((int)(k >> 22) == p1) atomicAdd(&s_hist[(k >> 12) & 1023u], 1u);
        }
        __syncthreads();
        pivot_scan(s_hist, k1r, s_part, &s_pivot, &s_krem);
        const uint32_t pref2 = ((uint32_t)p1 << 10) | (uint32_t)s_pivot;
        const int k2r = s_krem;

        for (int i = t; i < NB; i += BLOCK) s_hist[i] = 0;
        __syncthreads();
        for (int j = t; j < N_COLS; j += BLOCK) {
            if (j == target) continue;
            const uint32_t k = f2key(rowp[j]);
            if ((k >> 12) == pref2) atomicAdd(&s_hist[(k >> 2) & 1023u], 1u);
        }
        __syncthreads();
        pivot_scan(s_hist, k2r, s_part, &s_pivot, &s_krem);
        const uint32_t pref3 = (pref2 << 10) | (uint32_t)s_pivot;
        const int k3r = s_krem;

        // final 2 bits
        for (int i = t; i < NB; i += BLOCK) s_hist[i] = 0;
        __syncthreads();
        for (int j = t; j < N_COLS; j += BLOCK) {
            if (j == target) continue;
            const uint32_t k = f2key(rowp[j]);
            if ((k >> 2) == pref3) atomicAdd(&s_hist[k & 3u], 1u);
        }
        __syncthreads();
        if (t == 0) {
            int running = 0;
            for (int b = 3; b >= 0; --b) {
                const int c = (int)s_hist[b];
                if (running < k3r && running + c >= k3r) {
                    s_pivot = b; s_krem = k3r - running;
                }
                running += c;
            }
        }
        __syncthreads();
        T = (pref3 << 2) | (uint32_t)s_pivot;
        tie = s_krem;

        for (int j = t; j < N_COLS; j += BLOCK) {
            if (j == target) continue;
            const uint32_t k = f2key(rowp[j]);
            if (k > T) local += softplus_f(key2f(k));
        }
    }

    // ---- block reduce + epilogue ----
    for (int off = 32; off > 0; off >>= 1) local += __shfl_down(local, off);
    if (lane == 0) s_wsum[wid] = local;
    __syncthreads();
    if (t == 0) {
        float tot = 0.0f;
        for (int w = 0; w < NWAVE; ++w) tot += s_wsum[w];
        tot += (float)tie * softplus_f(key2f(T));
        const float l_neg = tot / (float)K_HARD;
        const float l_pos = softplus_f(-pos);
        const float rowval = (DELTA_W * l_pos + l_neg) * (1.0f / (float)M_ROWS);
        atomicAdd(out, rowval);
    }
}

__global__ void mmcl_zero_out(float* out) { out[0] = 0.0f; }

extern "C" void kernel_launch(void* const* d_in, const int* in_sizes, int n_in,
                              void* d_out, int out_size, void* d_ws, size_t ws_size,
                              hipStream_t stream) {
    const float* inputs = (const float*)d_in[0];
    const int* targets = (const int*)d_in[1];
    float* out = (float*)d_out;
    mmcl_zero_out<<<1, 1, 0, stream>>>(out);
    mmcl_kernel<<<M_ROWS, BLOCK, 0, stream>>>(inputs, targets, out);
}

// Round 4
// 359.713 us; speedup vs baseline: 1.1935x; 1.0633x over previous
//
#include <hip/hip_runtime.h>
#include <stdint.h>

#define M_ROWS 4096
#define N_COLS 16384
#define K_HARD 163          // int(0.01 * (16384 - 1))
#define DELTA_W 5.0f
#define BLOCK  256
#define SLOTS  12           // per-thread slots; P(Binom(64,.0228)>12)~5e-9/thread
#define CAP    1024         // compacted cap (mean 373, sd 19)
#define NB     1024         // histogram bins
#define SMALL  64           // pivot-bin resolve cap (expect ~2)
#define THRESH 2.0f
#define KEY_MIN 0xC0000000u // f2key(2.0f)

__device__ __forceinline__ uint32_t f2key(float x) {
    uint32_t u = __float_as_uint(x);
    return u ^ (uint32_t)(((int32_t)u >> 31) | 0x80000000u);
}
__device__ __forceinline__ float key2f(uint32_t k) {
    uint32_t u = (k & 0x80000000u) ? (k & 0x7fffffffu) : ~k;
    return __uint_as_float(u);
}
__device__ __forceinline__ float softplus_f(float x) {
    return fmaxf(x, 0.0f) + log1pf(__expf(-fabsf(x)));
}

// fallback-only parallel pivot finder over NB ascending bins
__device__ void pivot_scan(const uint32_t* hist, int K,
                           int* part, int* pivot, int* krem) {
    const int t = threadIdx.x;
    const int bpt = NB / BLOCK;            // 4
    const int base = t * bpt;
    int mypart = 0;
    for (int i = 0; i < bpt; ++i) mypart += (int)hist[base + i];
    part[t] = mypart;
    __syncthreads();
    for (int off = 1; off < BLOCK; off <<= 1) {
        int v = part[t];
        if (t + off < BLOCK) v += part[t + off];
        __syncthreads();
        part[t] = v;
        __syncthreads();
    }
    const int above = part[t] - mypart;
    if (above < K && above + mypart >= K) {
        int running = above;
        for (int b = base + bpt - 1; b >= base; --b) {
            int c = (int)hist[b];
            if (running < K && running + c >= K) { *pivot = b; *krem = K - running; }
            running += c;
        }
    }
    __syncthreads();
}

__global__ __launch_bounds__(BLOCK) void mmcl_kernel(
        const float* __restrict__ inputs,
        const int* __restrict__ targets,
        float* __restrict__ out) {
    __shared__ float    s_slots_f[BLOCK * SLOTS];  // 12 KB; aliased as hist later
    __shared__ uint32_t s_cand[CAP];               // 4 KB; aliased as part in fallback
    __shared__ int s_wt[4], s_wm[4];
    __shared__ int s_found, s_pivot, s_krem, s_nsmall;
    __shared__ uint32_t s_skey[SMALL];
    __shared__ int s_sidx[SMALL];
    __shared__ float s_fw[4];

    const int row = blockIdx.x;
    const int t = threadIdx.x;
    const int lane = t & 63;
    const int wid = t >> 6;
    const float* rowp = inputs + (size_t)row * N_COLS;
    const int target = targets[row];

    if (t == 0) s_found = -1;

    // ---- streaming: branchless, divergence-free, loads hoist ----
    float* myslots = s_slots_f + t * SLOTS;
    uint32_t cnt = 0;
    const float4* rp4 = (const float4*)rowp;
#pragma unroll 4
    for (int it = 0; it < N_COLS / (BLOCK * 4); ++it) {
        const float4 v = rp4[it * BLOCK + t];
        myslots[min(cnt, (uint32_t)(SLOTS - 1))] = v.x; cnt += (v.x >= THRESH);
        myslots[min(cnt, (uint32_t)(SLOTS - 1))] = v.y; cnt += (v.y >= THRESH);
        myslots[min(cnt, (uint32_t)(SLOTS - 1))] = v.z; cnt += (v.z >= THRESH);
        myslots[min(cnt, (uint32_t)(SLOTS - 1))] = v.w; cnt += (v.w >= THRESH);
    }

    // ---- shfl scans: offsets + overflow detect (no LDS scan) ----
    const int stored = (int)min(cnt, (uint32_t)SLOTS);
    int inc = stored;
    for (int off = 1; off < 64; off <<= 1) {
        int y = __shfl_up(inc, off);
        if (lane >= off) inc += y;
    }
    int mx = (int)cnt;
    for (int off = 1; off < 64; off <<= 1)
        mx = max(mx, __shfl_xor(mx, off));
    if (lane == 63) { s_wt[wid] = inc; }
    if (lane == 0)  { s_wm[wid] = mx; }
    __syncthreads();   // B1
    const int w0 = s_wt[0], w1 = s_wt[1], w2 = s_wt[2], w3 = s_wt[3];
    const int total = w0 + w1 + w2 + w3;
    const int maxc = max(max(s_wm[0], s_wm[1]), max(s_wm[2], s_wm[3]));
    const int wbase = (wid > 0 ? w0 : 0) + (wid > 1 ? w1 : 0) + (wid > 2 ? w2 : 0);
    const int myoff = wbase + inc - stored;
    for (int c = 0; c < stored; ++c) {
        const int d = myoff + c;
        if (d < CAP) s_cand[d] = f2key(myslots[c]);
    }
    __syncthreads();   // B2

    // ---- remove one instance of the positive ----
    const float pos = rowp[target];
    const uint32_t tkey = f2key(pos);
    const int tclamp = min(total, CAP);
    if (pos >= THRESH) {
        for (int i = t; i < tclamp; i += BLOCK)
            if (s_cand[i] == tkey) { atomicCAS(&s_found, -1, i); break; }
    }
    __syncthreads();   // B3
    int ncand = total;
    if (s_found >= 0) {
        ncand = total - 1;
        if (t == 0) s_cand[s_found] = s_cand[ncand];
    }
    __syncthreads();   // B4

    const bool fast = (maxc <= SLOTS) && (total <= CAP) && (ncand >= K_HARD);
    bool needfb = !fast;
    float local = 0.0f;

    uint32_t* hist = (uint32_t*)s_slots_f;   // alias: s_slots reads done pre-B2

    if (fast) {
        // ---- one-level histogram on key bits [23:14] (biased) ----
        for (int i = t; i < NB; i += BLOCK) hist[i] = 0;
        __syncthreads();   // B5
        for (int i = t; i < ncand; i += BLOCK)
            atomicAdd(&hist[min((s_cand[i] - KEY_MIN) >> 14, (uint32_t)(NB - 1))], 1u);
        __syncthreads();   // B6

        // ---- shfl suffix scan to locate pivot bin ----
        const int base4 = t * 4;
        const int c0 = (int)hist[base4], c1 = (int)hist[base4 + 1],
                  c2 = (int)hist[base4 + 2], c3 = (int)hist[base4 + 3];
        const int own = c0 + c1 + c2 + c3;
        int suf = own;
        for (int off = 1; off < 64; off <<= 1) {
            int y = __shfl_down(suf, off);
            if (lane + off < 64) suf += y;
        }
        if (lane == 0) s_wt[wid] = suf;      // wave total
        if (t == 0) s_nsmall = 0;
        __syncthreads();   // B7
        int wsuf = 0;
        for (int w = wid + 1; w < 4; ++w) wsuf += s_wt[w];
        int run = wsuf + (suf - own);        // count in bins strictly above mine
        {
            const int cs[4] = {c0, c1, c2, c3};
            for (int b = 3; b >= 0; --b) {
                const int c = cs[b];
                if (run < K_HARD && run + c >= K_HARD) {
                    s_pivot = base4 + b; s_krem = K_HARD - run;
                }
                run += c;
            }
        }
        __syncthreads();   // B8
        const uint32_t B = (uint32_t)s_pivot;
        const int krem = s_krem;

        // ---- sure set + collect pivot-bin members ----
        for (int i = t; i < ncand; i += BLOCK) {
            const uint32_t k = s_cand[i];
            const uint32_t kb = min((k - KEY_MIN) >> 14, (uint32_t)(NB - 1));
            if (kb > B) local += softplus_f(key2f(k));
            else if (kb == B) {
                const int d = atomicAdd(&s_nsmall, 1);
                if (d < SMALL) { s_skey[d] = k; s_sidx[d] = i; }
            }
        }
        __syncthreads();   // B9
        const int m = s_nsmall;
        if (m > SMALL) { needfb = true; local = 0.0f; }
        else {
            // exact resolve: take krem largest (key desc, index asc) of m
            for (int i = t; i < m; i += BLOCK) {
                const uint32_t ki = s_skey[i]; const int ii = s_sidx[i];
                int r = 0;
                for (int j = 0; j < m; ++j) {
                    const uint32_t kj = s_skey[j];
                    r += (kj > ki) || (kj == ki && s_sidx[j] < ii);
                }
                if (r < krem) local += softplus_f(key2f(ki));
            }
        }
    }

    if (needfb) {
        // ---- generic exact fallback: 10+10+10+2 radix from global ----
        local = 0.0f;
        int* part = (int*)s_cand;
        for (int i = t; i < NB; i += BLOCK) hist[i] = 0;
        __syncthreads();
        for (int j = t; j < N_COLS; j += BLOCK) {
            if (j == target) continue;
            atomicAdd(&hist[f2key(rowp[j]) >> 22], 1u);
        }
        __syncthreads();
        pivot_scan(hist, K_HARD, part, &s_pivot, &s_krem);
        const int p1 = s_pivot, k1r = s_krem;

        for (int i = t; i < NB; i += BLOCK) hist[i] = 0;
        __syncthreads();
        for (int j = t; j < N_COLS; j += BLOCK) {
            if (j == target) continue;
            const uint32_t k = f2key(rowp[j]);
            if ((int)(k >> 22) == p1) atomicAdd(&hist[(k >> 12) & 1023u], 1u);
        }
        __syncthreads();
        pivot_scan(hist, k1r, part, &s_pivot, &s_krem);
        const uint32_t pref2 = ((uint32_t)p1 << 10) | (uint32_t)s_pivot;
        const int k2r = s_krem;

        for (int i = t; i < NB; i += BLOCK) hist[i] = 0;
        __syncthreads();
        for (int j = t; j < N_COLS; j += BLOCK) {
            if (j == target) continue;
            const uint32_t k = f2key(rowp[j]);
            if ((k >> 12) == pref2) atomicAdd(&hist[(k >> 2) & 1023u], 1u);
        }
        __syncthreads();
        pivot_scan(hist, k2r, part, &s_pivot, &s_krem);
        const uint32_t pref3 = (pref2 << 10) | (uint32_t)s_pivot;
        const int k3r = s_krem;

        for (int i = t; i < 4; i += BLOCK) hist[i] = 0;
        __syncthreads();
        for (int j = t; j < N_COLS; j += BLOCK) {
            if (j == target) continue;
            const uint32_t k = f2key(rowp[j]);
            if ((k >> 2) == pref3) atomicAdd(&hist[k & 3u], 1u);
        }
        __syncthreads();
        if (t == 0) {
            int running = 0;
            for (int b = 3; b >= 0; --b) {
                const int c = (int)hist[b];
                if (running < k3r && running + c >= k3r) {
                    s_pivot = b; s_krem = k3r - running;
                }
                running += c;
            }
        }
        __syncthreads();
        const uint32_t T = (pref3 << 2) | (uint32_t)s_pivot;
        const int tie = s_krem;

        for (int j = t; j < N_COLS; j += BLOCK) {
            if (j == target) continue;
            const uint32_t k = f2key(rowp[j]);
            if (k > T) local += softplus_f(key2f(k));
        }
        if (t == 0) local += (float)tie * softplus_f(key2f(T));
    }

    // ---- block reduce + epilogue ----
    for (int off = 32; off > 0; off >>= 1) local += __shfl_down(local, off);
    if (lane == 0) s_fw[wid] = local;
    __syncthreads();
    if (t == 0) {
        const float tot = s_fw[0] + s_fw[1] + s_fw[2] + s_fw[3];
        const float l_neg = tot / (float)K_HARD;
        const float l_pos = softplus_f(-pos);
        const float rowval = (DELTA_W * l_pos + l_neg) * (1.0f / (float)M_ROWS);
        atomicAdd(out, rowval);
    }
}

__global__ void mmcl_zero_out(float* out) { out[0] = 0.0f; }

extern "C" void kernel_launch(void* const* d_in, const int* in_sizes, int n_in,
                              void* d_out, int out_size, void* d_ws, size_t ws_size,
                              hipStream_t stream) {
    const float* inputs = (const float*)d_in[0];
    const int* targets = (const int*)d_in[1];
    float* out = (float*)d_out;
    mmcl_zero_out<<<1, 1, 0, stream>>>(out);
    mmcl_kernel<<<M_ROWS, BLOCK, 0, stream>>>(inputs, targets, out);
}